// Round 4
// baseline (238.859 us; speedup 1.0000x reference)
//
#include <hip/hip_runtime.h>
#include <math.h>

// features [B,H,W,D,F] = [16,128,128,8,16] float32
// Reference: rotate(40deg,NN,fill=0) -> roll((5,-7),(H,W)) -> flip(W,D)
// Gather form (verified exact in R1, absmax 0):
//   out[b,h,w,d,f] = valid(i,j) ? in[b, si, sj, 7-d, f] : 0
//   i=(h+123)&127, j=(134-w)&127, (si,sj)=rint(R^-1(i,j)) about (63.5,63.5)
//
// R4: SCATTER formulation. A rotation forces 512B-granule scatter on exactly
// one side; reads stall waves on page-miss latency, writes are posted and
// L2/MALL-absorbed. So: iterate SOURCE space (reads perfectly linear), forward-
// rotate each source block, verify the <=4 candidate outputs in the 2x2 window
// with the exact inverse map (rotated unit cell half-extent (c+s)/2=0.705 < 1
// => window provably sufficient; each output claimed exactly once).
// Invalid outputs (~17%, never claimed) zeroed by a second, disjoint kernel.

typedef float f32x4 __attribute__((ext_vector_type(4)));

#define HH 128
#define WW 128

__global__ __launch_bounds__(256) void aug_scatter(const f32x4* __restrict__ in,
                                                   f32x4* __restrict__ out) {
    int tid = blockIdx.x * 256 + threadIdx.x;
    f32x4 v = in[tid];               // perfectly linear streaming read

    int q    = tid & 31;             // lane within 512B source block
    int f4   = q & 3;
    int dd   = q >> 2;               // source d index
    int sblk = tid >> 5;             // source block id = ((b*128+si)*128+sj)
    int sj = sblk & 127;
    int si = (sblk >> 7) & 127;
    int b  = sblk >> 14;

    const double c = 0.76604444311897803;  // cos(40 deg)
    const double s = 0.64278760968653933;  // sin(40 deg)
    double dsi = (double)si - 63.5;
    double dsj = (double)sj - 63.5;
    // forward rotation (inverse of the sampling map)
    double fi = c * dsi - s * dsj + 63.5;
    double fj = s * dsi + c * dsj + 63.5;
    int i0 = (int)floor(fi);
    int j0 = (int)floor(fj);

    int d_out = 7 - dd;              // D-flip
    long long base_b = (long long)b * (HH * WW * 8 * 4);  // float4 units

    #pragma unroll
    for (int ci = 0; ci < 2; ++ci) {
        int i = i0 + ci;
        if ((unsigned)i >= 128u) continue;
        double di = (double)i - 63.5;
        #pragma unroll
        for (int cj = 0; cj < 2; ++cj) {
            int j = j0 + cj;
            if ((unsigned)j >= 128u) continue;
            double dj = (double)j - 63.5;
            // exact inverse-map check (identical arithmetic to the gather)
            int ri = (int)rint(c * di + s * dj + 63.5);
            int rj = (int)rint(-s * di + c * dj + 63.5);
            if (ri == si && rj == sj) {
                int h = (i + 5) & 127;      // undo roll on H
                int w = (134 - j) & 127;    // undo roll+flip on W
                long long dst = base_b + (long long)(((h * WW + w) * 8 + d_out) * 4 + f4);
                out[dst] = v;               // posted 512B-granule scatter
            }
        }
    }
}

// Zero the never-claimed (invalid) outputs. Disjoint from aug_scatter's set.
// 524288 threads: t = (((h*128 + w)*16 + b)*2 + half); 32 consecutive lanes
// share one (h,w) -> uniform predicate per half-wave.
__global__ __launch_bounds__(256) void aug_zero_invalid(f32x4* __restrict__ out) {
    int t = blockIdx.x * 256 + threadIdx.x;
    int half = t & 1;
    int b = (t >> 1) & 15;
    int w = (t >> 5) & 127;
    int h = t >> 12;

    int i = (h + 123) & 127;
    int j = (134 - w) & 127;
    const double c = 0.76604444311897803;
    const double s = 0.64278760968653933;
    double di = (double)i - 63.5;
    double dj = (double)j - 63.5;
    int si = (int)rint(c * di + s * dj + 63.5);
    int sj = (int)rint(-s * di + c * dj + 63.5);
    if ((unsigned)si < 128u && (unsigned)sj < 128u) return;  // valid -> claimed

    long long base = ((long long)((b * 128 + h) * 128 + w)) * 32 + half * 16;
    f32x4 z = (f32x4)(0.f);
    #pragma unroll
    for (int k = 0; k < 16; ++k) out[base + k] = z;
}

extern "C" void kernel_launch(void* const* d_in, const int* in_sizes, int n_in,
                              void* d_out, int out_size, void* d_ws, size_t ws_size,
                              hipStream_t stream) {
    const f32x4* in = (const f32x4*)d_in[0];
    f32x4* out = (f32x4*)d_out;
    // 8388608 float4 of input -> 32768 blocks x 256 threads
    aug_scatter<<<32768, 256, 0, stream>>>(in, out);
    // 524288 threads -> 2048 blocks
    aug_zero_invalid<<<2048, 256, 0, stream>>>(out);
}